// Round 2
// baseline (695.042 us; speedup 1.0000x reference)
//
#include <hip/hip_runtime.h>
#include <hip/hip_bf16.h>

#define DIM   128
#define NREL  3
#define KS    (NREL*DIM)     // 384
#define KTOT  (KS + DIM)     // 512
#define NB    16             // nodes per block in main kernel
#define LN_EPS 1e-5f

typedef __hip_bfloat16 bf16;

__device__ __forceinline__ float bits_to_f(unsigned short u) {
    union { unsigned int i; float f; } cv; cv.i = ((unsigned int)u) << 16; return cv.f;
}
// Load float input element i, honoring runtime dtype flag (1 = fp32, 0 = bf16)
__device__ __forceinline__ float loadf(const void* p, size_t i, int f32) {
    return f32 ? ((const float*)p)[i]
               : bits_to_f(((const unsigned short*)p)[i]);
}
// Index element i from an "int" input that may really be int64 (i64 flag)
__device__ __forceinline__ int ldidx(const int* p, size_t i, int i64) {
    return i64 ? p[2*i] : p[i];
}

// ---------------------------------------------------------------------------
// Probe: flags[0]=1 if float inputs are fp32 (else bf16);
//        flags[1]=1 if integer inputs are int64 words (else int32).
// ---------------------------------------------------------------------------
__global__ void probe_kernel(const unsigned short* __restrict__ x16,
                             const int* __restrict__ ei,
                             int* __restrict__ flags)
{
    if (blockIdx.x == 0 && threadIdx.x == 0) {
        int sane = 0;
        for (int i = 0; i < 256; i++) {
            unsigned e = (x16[i] >> 7) & 0xFF;      // bf16 exponent field
            if (e >= 107 && e <= 147) sane++;       // |v| in [2^-20, 2^20]
        }
        flags[0] = (sane < 224) ? 1 : 0;
        int zeros = 0;
        for (int i = 0; i < 256; i++) if (ei[i] == 0) zeros++;
        flags[1] = (zeros > 64) ? 1 : 0;
    }
}

// ---------------------------------------------------------------------------
// Histogram of dst
// ---------------------------------------------------------------------------
__global__ void hist_kernel(const int* __restrict__ ei, int E,
                            int* __restrict__ cnt,
                            const int* __restrict__ flags)
{
    int e = blockIdx.x * blockDim.x + threadIdx.x;
    if (e >= E) return;
    int i64 = flags[1];
    int d = ldidx(ei, (size_t)E + e, i64);
    atomicAdd(&cnt[d], 1);
}

// ---------------------------------------------------------------------------
// Exclusive scan of cnt[0..N) -> offs[0..N], also copies to cur[0..N)
// Single block, 256 threads, each handles a contiguous chunk.
// ---------------------------------------------------------------------------
__global__ void scan_kernel(const int* __restrict__ cnt,
                            int* __restrict__ offs,
                            int* __restrict__ cur, int N)
{
    __shared__ int part[256];
    int t = threadIdx.x;
    int L = (N + 255) / 256;
    int lo = t * L;
    int hi = min(lo + L, N);
    if (hi < lo) hi = lo;
    int s = 0;
    for (int k = lo; k < hi; k++) s += cnt[k];
    part[t] = s;
    __syncthreads();
    // Hillis-Steele inclusive scan
    for (int off = 1; off < 256; off <<= 1) {
        int v = part[t];
        int add = (t >= off) ? part[t - off] : 0;
        __syncthreads();
        part[t] = v + add;
        __syncthreads();
    }
    int base = (t == 0) ? 0 : part[t - 1];
    int run = base;
    for (int k = lo; k < hi; k++) { offs[k] = run; cur[k] = run; run += cnt[k]; }
    if (t == 255) offs[N] = run;
}

// ---------------------------------------------------------------------------
// Fill CSR slots: epack[slot] = src | (type<<17)
// ---------------------------------------------------------------------------
__global__ void fill_kernel(const int* __restrict__ ei,
                            const int* __restrict__ et, int E,
                            int* __restrict__ cur,
                            int* __restrict__ epack,
                            const int* __restrict__ flags)
{
    int e = blockIdx.x * blockDim.x + threadIdx.x;
    if (e >= E) return;
    int i64 = flags[1];
    int s = ldidx(ei, (size_t)e, i64);
    int d = ldidx(ei, (size_t)E + e, i64);
    int r = ldidx(et, (size_t)e, i64);
    int p = atomicAdd(&cur[d], 1);
    epack[p] = s | (r << 17);
}

// ---------------------------------------------------------------------------
// Pack Wbig (rows 0..383 = relation_weights[r][k][:], rows 384..511 = lin_w^T)
// as float4 chunks: Wpack[(c*DIM+d)*4 + i] = Wbig[4c+i][d]
// ---------------------------------------------------------------------------
__global__ void build_wpack(const void* __restrict__ relw,
                            const void* __restrict__ linw,
                            float* __restrict__ Wpack,
                            const int* __restrict__ flags)
{
    int idx = blockIdx.x * blockDim.x + threadIdx.x;
    if (idx >= (KTOT/4)*DIM) return;
    int f32 = flags[0];
    int c = idx / DIM;
    int d = idx - c*DIM;
    float tmp[4];
    #pragma unroll
    for (int i = 0; i < 4; i++) {
        int row = 4*c + i;
        tmp[i] = (row < KS) ? loadf(relw, (size_t)row*DIM + d, f32)
                            : loadf(linw, (size_t)d*DIM + (row - KS), f32);
    }
    float4 v; v.x = tmp[0]; v.y = tmp[1]; v.z = tmp[2]; v.w = tmp[3];
    ((float4*)Wpack)[idx] = v;
}

// ---------------------------------------------------------------------------
// Main: gather per-relation sums via CSR, build A = [S/deg | x], GEMM vs
// Wbig, +bias, LayerNorm, store.
// ---------------------------------------------------------------------------
__global__ __launch_bounds__(128)
void main_kernel(const void* __restrict__ x,
                 const int* __restrict__ offs,
                 const int* __restrict__ epack,
                 const float* __restrict__ Wpack,
                 const void* __restrict__ linb,
                 const void* __restrict__ gamma,
                 const void* __restrict__ beta,
                 void* __restrict__ out,
                 int N, const int* __restrict__ flags)
{
    __shared__ float A[NB][KTOT];          // 32 KiB
    __shared__ float s_mu[NB], s_rs[NB];

    const int t  = threadIdx.x;            // 0..127
    const int n0 = blockIdx.x * NB;
    const int f32 = flags[0];

    // Gather phase: per node, per-relation sums across incoming edges
    for (int j = 0; j < NB; j++) {
        int n = n0 + j;
        float a0 = 0.f, a1 = 0.f, a2 = 0.f, xv = 0.f;
        int c = 0;
        if (n < N) {
            int beg = offs[n], end = offs[n+1];
            c = end - beg;
            for (int p = beg; p < end; p++) {
                int pk = epack[p];
                int s  = pk & 0x1FFFF;
                int r  = pk >> 17;
                float v = loadf(x, (size_t)s*DIM + t, f32);
                if (r == 0) a0 += v; else if (r == 1) a1 += v; else a2 += v;
            }
            xv = loadf(x, (size_t)n*DIM + t, f32);
        }
        float inv = 1.0f / fmaxf((float)c, 1.0f);
        A[j][0*DIM + t] = a0 * inv;
        A[j][1*DIM + t] = a1 * inv;
        A[j][2*DIM + t] = a2 * inv;
        A[j][3*DIM + t] = xv;
    }
    __syncthreads();

    const int d = t;
    float acc[NB];
    #pragma unroll
    for (int j = 0; j < NB; j++) acc[j] = 0.0f;

    const float4* Wp = (const float4*)Wpack;
    for (int c = 0; c < KTOT/4; c++) {
        float4 w = Wp[c*DIM + d];
        #pragma unroll
        for (int j = 0; j < NB; j++) {
            float4 a = *(const float4*)&A[j][4*c];
            acc[j] += a.x*w.x + a.y*w.y + a.z*w.z + a.w*w.w;
        }
    }

    float lb = loadf(linb, d, f32);
    #pragma unroll
    for (int j = 0; j < NB; j++) acc[j] += lb;

    __syncthreads();                        // done reading A — reuse as H
    float* H = &A[0][0];
    #pragma unroll
    for (int j = 0; j < NB; j++) H[j*DIM + d] = acc[j];
    __syncthreads();

    {
        int j = t >> 3, p = t & 7;
        float s1 = 0.f, s2 = 0.f;
        const float* hr = &H[j*DIM + p*16];
        #pragma unroll
        for (int i = 0; i < 16; i++) { float v = hr[i]; s1 += v; s2 += v*v; }
        #pragma unroll
        for (int off = 1; off < 8; off <<= 1) {
            s1 += __shfl_xor(s1, off);
            s2 += __shfl_xor(s2, off);
        }
        if (p == 0) {
            float mu  = s1 * (1.0f/DIM);
            float var = s2 * (1.0f/DIM) - mu*mu;
            s_mu[j] = mu;
            s_rs[j] = rsqrtf(var + LN_EPS);
        }
    }
    __syncthreads();

    float g = loadf(gamma, d, f32);
    float b = loadf(beta,  d, f32);
    #pragma unroll
    for (int j = 0; j < NB; j++) {
        int n = n0 + j;
        if (n < N) {
            float o = g * (acc[j] - s_mu[j]) * s_rs[j] + b;
            size_t oi = (size_t)n*DIM + d;
            if (f32) ((float*)out)[oi] = o;
            else     ((bf16*)out)[oi] = __float2bfloat16(o);
        }
    }
}

extern "C" void kernel_launch(void* const* d_in, const int* in_sizes, int n_in,
                              void* d_out, int out_size, void* d_ws, size_t ws_size,
                              hipStream_t stream)
{
    const void* x   = d_in[0];
    const int*  ei  = (const int*)d_in[1];
    const int*  et  = (const int*)d_in[2];
    const void* rw  = d_in[3];
    const void* lw  = d_in[4];
    const void* lb  = d_in[5];
    const void* lg  = d_in[6];
    const void* lbe = d_in[7];

    const int N = in_sizes[0] / DIM;
    const int E = in_sizes[2];

    // ws layout (all within ~3.3 MB)
    char* w = (char*)d_ws;
    int* flags = (int*)w;                 w += 16;
    int* cnt   = (int*)w;                 w += (size_t)N * 4;
    int* offs  = (int*)w;                 w += (size_t)(N+1) * 4;
    int* cur   = (int*)w;                 w += (size_t)N * 4;
    int* epack = (int*)w;                 w += (size_t)E * 4;
    w = (char*)(((uintptr_t)w + 15) & ~(uintptr_t)15);
    float* Wp  = (float*)w;               // 512*128 floats = 256 KiB

    hipMemsetAsync(cnt, 0, (size_t)N * 4, stream);

    probe_kernel<<<1, 64, 0, stream>>>((const unsigned short*)x, ei, flags);
    hist_kernel<<<(E + 255)/256, 256, 0, stream>>>(ei, E, cnt, flags);
    scan_kernel<<<1, 256, 0, stream>>>(cnt, offs, cur, N);
    fill_kernel<<<(E + 255)/256, 256, 0, stream>>>(ei, et, E, cur, epack, flags);
    build_wpack<<<((KTOT/4)*DIM + 255)/256, 256, 0, stream>>>(rw, lw, Wp, flags);

    main_kernel<<<(N + NB - 1)/NB, 128, 0, stream>>>(x, offs, epack, Wp,
                                                     lb, lg, lbe, d_out, N, flags);
}

// Round 5
// 550.448 us; speedup vs baseline: 1.2627x; 1.2627x over previous
//
#include <hip/hip_runtime.h>
#include <hip/hip_bf16.h>

#define DIM   128
#define NREL  3
#define KS    (NREL*DIM)     // 384
#define KTOT  (KS + DIM)     // 512
#define NB    16             // nodes per block in main kernel
#define AST   (KTOT + 8)     // padded LDS row stride (floats)
#define LN_EPS 1e-5f

typedef __hip_bfloat16 bf16;
typedef unsigned int uint;
typedef float f32x4 __attribute__((ext_vector_type(4)));
typedef short short8 __attribute__((ext_vector_type(8)));

__device__ __forceinline__ float bits_to_f(unsigned short u) {
    union { uint i; float f; } cv; cv.i = ((uint)u) << 16; return cv.f;
}
__device__ __forceinline__ unsigned short f2bf(float f) {   // round-to-nearest-even
    union { float f; uint u; } c; c.f = f;
    return (unsigned short)((c.u + 0x7fffu + ((c.u >> 16) & 1u)) >> 16);
}
// Load float input element i, honoring runtime dtype flag (1 = fp32, 0 = bf16)
__device__ __forceinline__ float loadf(const void* p, size_t i, int f32) {
    return f32 ? ((const float*)p)[i]
               : bits_to_f(((const unsigned short*)p)[i]);
}
// Index element i from an "int" input that may really be int64 (i64 flag)
__device__ __forceinline__ int ldidx(const int* p, size_t i, int i64) {
    return i64 ? p[2*i] : p[i];
}

// ---------------------------------------------------------------------------
// Probe: flags[0]=1 if float inputs are fp32 (else bf16);
//        flags[1]=1 if integer inputs are int64 words (else int32).
// ---------------------------------------------------------------------------
__global__ void probe_kernel(const unsigned short* __restrict__ x16,
                             const int* __restrict__ ei,
                             int* __restrict__ flags)
{
    if (blockIdx.x == 0 && threadIdx.x == 0) {
        int sane = 0;
        for (int i = 0; i < 256; i++) {
            unsigned e = (x16[i] >> 7) & 0xFF;      // bf16 exponent field
            if (e >= 107 && e <= 147) sane++;       // |v| in [2^-20, 2^20]
        }
        flags[0] = (sane < 224) ? 1 : 0;
        int zeros = 0;
        for (int i = 0; i < 256; i++) if (ei[i] == 0) zeros++;
        flags[1] = (zeros > 64) ? 1 : 0;
    }
}

// ---------------------------------------------------------------------------
// Histogram of dst
// ---------------------------------------------------------------------------
__global__ void hist_kernel(const int* __restrict__ ei, int E,
                            int* __restrict__ cnt,
                            const int* __restrict__ flags)
{
    int e = blockIdx.x * blockDim.x + threadIdx.x;
    if (e >= E) return;
    int i64 = flags[1];
    int d = ldidx(ei, (size_t)E + e, i64);
    atomicAdd(&cnt[d], 1);
}

// ---------------------------------------------------------------------------
// Exclusive scan of cnt[0..N) -> offs[0..N], also copies to cur[0..N)
// ---------------------------------------------------------------------------
__global__ void scan_kernel(const int* __restrict__ cnt,
                            int* __restrict__ offs,
                            int* __restrict__ cur, int N)
{
    __shared__ int part[256];
    int t = threadIdx.x;
    int L = (N + 255) / 256;
    int lo = t * L;
    int hi = min(lo + L, N);
    if (hi < lo) hi = lo;
    int s = 0;
    for (int k = lo; k < hi; k++) s += cnt[k];
    part[t] = s;
    __syncthreads();
    for (int off = 1; off < 256; off <<= 1) {
        int v = part[t];
        int add = (t >= off) ? part[t - off] : 0;
        __syncthreads();
        part[t] = v + add;
        __syncthreads();
    }
    int base = (t == 0) ? 0 : part[t - 1];
    int run = base;
    for (int k = lo; k < hi; k++) { offs[k] = run; cur[k] = run; run += cnt[k]; }
    if (t == 255) offs[N] = run;
}

// ---------------------------------------------------------------------------
// Fill CSR slots: epack[slot] = src | (type<<17)
// ---------------------------------------------------------------------------
__global__ void fill_kernel(const int* __restrict__ ei,
                            const int* __restrict__ et, int E,
                            int* __restrict__ cur,
                            int* __restrict__ epack,
                            const int* __restrict__ flags)
{
    int e = blockIdx.x * blockDim.x + threadIdx.x;
    if (e >= E) return;
    int i64 = flags[1];
    int s = ldidx(ei, (size_t)e, i64);
    int d = ldidx(ei, (size_t)E + e, i64);
    int r = ldidx(et, (size_t)e, i64);
    int p = atomicAdd(&cur[d], 1);
    epack[p] = s | (r << 17);
}

// ---------------------------------------------------------------------------
// Pack Wbig into B-fragment order (bf16) for mfma_f32_16x16x32_bf16.
// Wbig[k][n]: k<384 -> relation_weights[k*128+n]; k>=384 -> lin_w[n*128+(k-384)]
// B-frag: lane = q*16 + (n&15), element j = Wbig[kk*32 + q*8 + j][n]
// ---------------------------------------------------------------------------
__global__ void build_b(const void* __restrict__ relw,
                        const void* __restrict__ linw,
                        unsigned short* __restrict__ Bpack,
                        const int* __restrict__ flags)
{
    int idx = blockIdx.x * 256 + threadIdx.x;   // 0..8191 (16B slots)
    if (idx >= 8192) return;
    int f32 = flags[0];
    int lane = idx & 63, kk = (idx >> 6) & 15, tile = idx >> 10;
    int q = lane >> 4, n = tile * 16 + (lane & 15);
    uint vv[4];
    #pragma unroll
    for (int jp = 0; jp < 4; jp++) {
        int k0 = kk * 32 + q * 8 + jp * 2;
        float v0 = (k0     < KS) ? loadf(relw, (size_t)k0*DIM + n, f32)
                                 : loadf(linw, (size_t)n*DIM + (k0 - KS), f32);
        float v1 = (k0 + 1 < KS) ? loadf(relw, (size_t)(k0+1)*DIM + n, f32)
                                 : loadf(linw, (size_t)n*DIM + (k0 + 1 - KS), f32);
        vv[jp] = (uint)f2bf(v0) | ((uint)f2bf(v1) << 16);
    }
    uint4 v; v.x = vv[0]; v.y = vv[1]; v.z = vv[2]; v.w = vv[3];
    ((uint4*)Bpack)[idx] = v;
}

// ---------------------------------------------------------------------------
// Main: R2's gather (verbatim, padded stride) -> in-register bf16 A-frags ->
// MFMA vs Bpack -> +bias -> R2's LN -> out.  128 threads, 16 nodes/block.
// ---------------------------------------------------------------------------
__global__ __launch_bounds__(128)
void main_kernel(const void* __restrict__ x,
                 const int* __restrict__ offs,
                 const int* __restrict__ epack,
                 const unsigned short* __restrict__ Bpack,
                 const void* __restrict__ linb,
                 const void* __restrict__ gamma,
                 const void* __restrict__ beta,
                 void* __restrict__ out,
                 int N, const int* __restrict__ flags)
{
    __shared__ float A[NB * AST];           // 33,280 B; reused as H[16][132]
    __shared__ float s_mu[NB], s_rs[NB];

    const int t  = threadIdx.x;             // 0..127
    const int n0 = blockIdx.x * NB;
    const int f32 = flags[0];

    // ---------------- gather (R2 verbatim, stride AST) ----------------
    for (int j = 0; j < NB; j++) {
        int n = n0 + j;
        float a0 = 0.f, a1 = 0.f, a2 = 0.f, xv = 0.f;
        int c = 0;
        if (n < N) {
            int beg = offs[n], end = offs[n+1];
            c = end - beg;
            for (int p = beg; p < end; p++) {
                int pk = epack[p];
                int s  = pk & 0x1FFFF;
                int r  = pk >> 17;
                float v = loadf(x, (size_t)s*DIM + t, f32);
                if (r == 0) a0 += v; else if (r == 1) a1 += v; else a2 += v;
            }
            xv = loadf(x, (size_t)n*DIM + t, f32);
        }
        float inv = 1.0f / fmaxf((float)c, 1.0f);
        A[j*AST + 0*DIM + t] = a0 * inv;
        A[j*AST + 1*DIM + t] = a1 * inv;
        A[j*AST + 2*DIM + t] = a2 * inv;
        A[j*AST + 3*DIM + t] = xv;
    }
    __syncthreads();

    // ---------------- MFMA GEMM ----------------
    const int lane = t & 63;
    const int w    = t >> 6;                // 0..1 (wave)
    const int mm   = lane & 15;             // A row (node)
    const int q    = lane >> 4;             // k-octet selector
    f32x4 acc0 = {0,0,0,0}, acc1 = {0,0,0,0}, acc2 = {0,0,0,0}, acc3 = {0,0,0,0};
    {
        const short8* Bq = (const short8*)Bpack;
        #pragma unroll
        for (int kk = 0; kk < 16; kk++) {
            const float* ap = &A[mm*AST + kk*32 + q*8];
            float4 f0 = *(const float4*)ap;
            float4 f1 = *(const float4*)(ap + 4);
            union { short8 s; unsigned short u[8]; } af;
            af.u[0] = f2bf(f0.x); af.u[1] = f2bf(f0.y);
            af.u[2] = f2bf(f0.z); af.u[3] = f2bf(f0.w);
            af.u[4] = f2bf(f1.x); af.u[5] = f2bf(f1.y);
            af.u[6] = f2bf(f1.z); af.u[7] = f2bf(f1.w);
            short8 b0 = Bq[((w*4 + 0)*16 + kk)*64 + lane];
            short8 b1 = Bq[((w*4 + 1)*16 + kk)*64 + lane];
            short8 b2 = Bq[((w*4 + 2)*16 + kk)*64 + lane];
            short8 b3 = Bq[((w*4 + 3)*16 + kk)*64 + lane];
            acc0 = __builtin_amdgcn_mfma_f32_16x16x32_bf16(af.s, b0, acc0, 0, 0, 0);
            acc1 = __builtin_amdgcn_mfma_f32_16x16x32_bf16(af.s, b1, acc1, 0, 0, 0);
            acc2 = __builtin_amdgcn_mfma_f32_16x16x32_bf16(af.s, b2, acc2, 0, 0, 0);
            acc3 = __builtin_amdgcn_mfma_f32_16x16x32_bf16(af.s, b3, acc3, 0, 0, 0);
        }
    }
    __syncthreads();                        // all A reads done; reuse as H

    float* H = A;                           // H[16][132]
    {
        // C/D layout: col = lane&15, row = (lane>>4)*4 + i
        int rb = q * 4;
        #pragma unroll
        for (int nt = 0; nt < 4; nt++) {
            int d = (w*4 + nt)*16 + mm;
            float lb = loadf(linb, d, f32);
            f32x4 a = (nt == 0) ? acc0 : (nt == 1) ? acc1 : (nt == 2) ? acc2 : acc3;
            #pragma unroll
            for (int i = 0; i < 4; i++)
                H[(rb + i)*132 + d] = a[i] + lb;
        }
    }
    __syncthreads();

    // ---------------- LayerNorm stats (R2 verbatim) ----------------
    {
        int j = t >> 3, p = t & 7;
        float s1 = 0.f, s2 = 0.f;
        const float* hr = &H[j*132 + p*16];
        #pragma unroll
        for (int i = 0; i < 16; i++) { float v = hr[i]; s1 += v; s2 += v*v; }
        #pragma unroll
        for (int off = 1; off < 8; off <<= 1) {
            s1 += __shfl_xor(s1, off);
            s2 += __shfl_xor(s2, off);
        }
        if (p == 0) {
            float mu  = s1 * (1.0f/DIM);
            float var = s2 * (1.0f/DIM) - mu*mu;
            s_mu[j] = mu;
            s_rs[j] = rsqrtf(var + LN_EPS);
        }
    }
    __syncthreads();

    // ---------------- output (R2 verbatim) ----------------
    {
        int d = t;
        float g = loadf(gamma, d, f32);
        float b = loadf(beta,  d, f32);
        for (int j = 0; j < NB; j++) {
            int n = n0 + j;
            if (n < N) {
                float hv = H[j*132 + d];
                float o = g * (hv - s_mu[j]) * s_rs[j] + b;
                size_t oi = (size_t)n*DIM + d;
                if (f32) ((float*)out)[oi] = o;
                else     ((bf16*)out)[oi] = __float2bfloat16(o);
            }
        }
    }
}

extern "C" void kernel_launch(void* const* d_in, const int* in_sizes, int n_in,
                              void* d_out, int out_size, void* d_ws, size_t ws_size,
                              hipStream_t stream)
{
    const void* x   = d_in[0];
    const int*  ei  = (const int*)d_in[1];
    const int*  et  = (const int*)d_in[2];
    const void* rw  = d_in[3];
    const void* lw  = d_in[4];
    const void* lb  = d_in[5];
    const void* lg  = d_in[6];
    const void* lbe = d_in[7];

    const int N = in_sizes[0] / DIM;
    const int E = in_sizes[2];

    // ws layout — EXACT R2 structure (known good), Bpack smaller than Wpack
    char* w = (char*)d_ws;
    int* flags = (int*)w;                 w += 16;
    int* cnt   = (int*)w;                 w += (size_t)N * 4;
    int* offs  = (int*)w;                 w += (size_t)(N+1) * 4;
    int* cur   = (int*)w;                 w += (size_t)N * 4;
    int* epack = (int*)w;                 w += (size_t)E * 4;
    w = (char*)(((uintptr_t)w + 15) & ~(uintptr_t)15);
    unsigned short* Bpack = (unsigned short*)w;    // 512*128 bf16 = 128 KiB

    hipMemsetAsync(cnt, 0, (size_t)N * 4, stream);

    probe_kernel<<<1, 64, 0, stream>>>((const unsigned short*)x, ei, flags);
    hist_kernel<<<(E + 255)/256, 256, 0, stream>>>(ei, E, cnt, flags);
    scan_kernel<<<1, 256, 0, stream>>>(cnt, offs, cur, N);
    fill_kernel<<<(E + 255)/256, 256, 0, stream>>>(ei, et, E, cur, epack, flags);
    build_b<<<32, 256, 0, stream>>>(rw, lw, Bpack, flags);

    main_kernel<<<(N + NB - 1)/NB, 128, 0, stream>>>(x, offs, epack, Bpack,
                                                     lb, lg, lbe, d_out, N, flags);
}

// Round 8
// 339.959 us; speedup vs baseline: 2.0445x; 1.6192x over previous
//
#include <hip/hip_runtime.h>
#include <hip/hip_bf16.h>

#define DIM   128
#define NREL  3
#define KS    (NREL*DIM)     // 384
#define KTOT  (KS + DIM)     // 512
#define NB    16             // nodes per block in main kernel
#define AST   (KTOT + 8)     // padded LDS row stride (floats)
#define LN_EPS 1e-5f

typedef unsigned int uint;
typedef float f32x4 __attribute__((ext_vector_type(4)));
typedef short short8 __attribute__((ext_vector_type(8)));

__device__ __forceinline__ unsigned short f2bf(float f) {   // round-to-nearest-even
    union { float f; uint u; } c; c.f = f;
    return (unsigned short)((c.u + 0x7fffu + ((c.u >> 16) & 1u)) >> 16);
}
// Index element i from an "int" input that may really be int64 (i64 flag)
__device__ __forceinline__ int ldidx(const int* p, size_t i, int i64) {
    return i64 ? p[2*i] : p[i];
}

// ---------------------------------------------------------------------------
// Probe int width: int64 storage => ~half of first 256 words are zero highs.
// ---------------------------------------------------------------------------
__global__ void probe_kernel(const int* __restrict__ ei, int* __restrict__ flags)
{
    int t = threadIdx.x;                    // 64 threads
    int z = 0;
    #pragma unroll
    for (int i = 0; i < 4; i++) z += (ei[t*4 + i] == 0) ? 1 : 0;
    #pragma unroll
    for (int off = 1; off < 64; off <<= 1) z += __shfl_xor(z, off);
    if (t == 0) flags[0] = (z > 64) ? 1 : 0;
}

// ---------------------------------------------------------------------------
// Histogram of dst
// ---------------------------------------------------------------------------
__global__ void hist_kernel(const int* __restrict__ ei, int E,
                            int* __restrict__ cnt,
                            const int* __restrict__ flags)
{
    int e = blockIdx.x * blockDim.x + threadIdx.x;
    if (e >= E) return;
    int i64 = flags[0];
    int d = ldidx(ei, (size_t)E + e, i64);
    atomicAdd(&cnt[d], 1);
}

// ---------------------------------------------------------------------------
// Exclusive scan of cnt[0..N) -> offs[0..N], also copies to cur[0..N)
// ---------------------------------------------------------------------------
__global__ __launch_bounds__(1024)
void scan_kernel(const int* __restrict__ cnt,
                 int* __restrict__ offs,
                 int* __restrict__ cur, int N)
{
    __shared__ int part[1024];
    int t = threadIdx.x;
    int L = (N + 1023) >> 10;
    int lo = t * L;
    int hi = min(lo + L, N);
    if (hi < lo) hi = lo;
    int s = 0;
    for (int k = lo; k < hi; k++) s += cnt[k];
    part[t] = s;
    __syncthreads();
    for (int off = 1; off < 1024; off <<= 1) {
        int v = part[t];
        int add = (t >= off) ? part[t - off] : 0;
        __syncthreads();
        part[t] = v + add;
        __syncthreads();
    }
    int run = (t == 0) ? 0 : part[t - 1];
    for (int k = lo; k < hi; k++) { offs[k] = run; cur[k] = run; run += cnt[k]; }
    if (t == 1023) offs[N] = part[1023];
}

// ---------------------------------------------------------------------------
// Fill CSR slots: epack[slot] = src | (type<<17)
// ---------------------------------------------------------------------------
__global__ void fill_kernel(const int* __restrict__ ei,
                            const int* __restrict__ et, int E,
                            int* __restrict__ cur,
                            int* __restrict__ epack,
                            const int* __restrict__ flags)
{
    int e = blockIdx.x * blockDim.x + threadIdx.x;
    if (e >= E) return;
    int i64 = flags[0];
    int s = ldidx(ei, (size_t)e, i64);
    int d = ldidx(ei, (size_t)E + e, i64);
    int r = ldidx(et, (size_t)e, i64);
    int p = atomicAdd(&cur[d], 1);
    epack[p] = s | (r << 17);
}

// ---------------------------------------------------------------------------
// Pack Wbig (fp32 in) into bf16 B-fragment order for mfma_f32_16x16x32_bf16.
// Wbig[k][n]: k<384 -> relation_weights[k*128+n]; k>=384 -> lin_w[n*128+(k-384)]
// B-frag: lane = q*16 + (n&15), element j = Wbig[kk*32 + q*8 + j][n]
// ---------------------------------------------------------------------------
__global__ void build_b(const float* __restrict__ relw,
                        const float* __restrict__ linw,
                        unsigned short* __restrict__ Bpack)
{
    int idx = blockIdx.x * 256 + threadIdx.x;   // 0..8191 (16B slots)
    if (idx >= 8192) return;
    int lane = idx & 63, kk = (idx >> 6) & 15, tile = idx >> 10;
    int q = lane >> 4, n = tile * 16 + (lane & 15);
    uint vv[4];
    #pragma unroll
    for (int jp = 0; jp < 4; jp++) {
        int k0 = kk * 32 + q * 8 + jp * 2;
        float v0 = (k0     < KS) ? relw[(size_t)k0*DIM + n]
                                 : linw[(size_t)n*DIM + (k0 - KS)];
        float v1 = (k0 + 1 < KS) ? relw[(size_t)(k0+1)*DIM + n]
                                 : linw[(size_t)n*DIM + (k0 + 1 - KS)];
        vv[jp] = (uint)f2bf(v0) | ((uint)f2bf(v1) << 16);
    }
    uint4 v; v.x = vv[0]; v.y = vv[1]; v.z = vv[2]; v.w = vv[3];
    ((uint4*)Bpack)[idx] = v;
}

// ---------------------------------------------------------------------------
// Main: parallel gather (8 thr/node, float4 loads, mask-FMA accumulate) ->
// fp32 LDS A -> in-register bf16 A-frags -> MFMA vs Bpack -> +bias -> LN.
// 128 threads, 16 nodes/block.
// ---------------------------------------------------------------------------
__global__ __launch_bounds__(128)
void main_kernel(const float* __restrict__ x,
                 const int* __restrict__ offs,
                 const int* __restrict__ epack,
                 const unsigned short* __restrict__ Bpack,
                 const float* __restrict__ linb,
                 const float* __restrict__ gamma,
                 const float* __restrict__ beta,
                 float* __restrict__ out,
                 int N)
{
    __shared__ float A[NB * AST];           // 33,280 B; reused as H[16][132]
    __shared__ float s_mu[NB], s_rs[NB];

    const int t  = threadIdx.x;             // 0..127
    const int n0 = blockIdx.x * NB;

    // ---------------- gather: 8 threads per node ----------------
    {
        const int m = t >> 3;               // node-local 0..15
        const int c = t & 7;                // float4 chunk; covers dims seg*32+c*4..+3
        const int n = n0 + m;
        float a0[16], a1[16], a2[16];       // [seg*4 + i]
        #pragma unroll
        for (int i = 0; i < 16; i++) { a0[i] = 0.f; a1[i] = 0.f; a2[i] = 0.f; }
        float4 xs[4] = { {0,0,0,0}, {0,0,0,0}, {0,0,0,0}, {0,0,0,0} };
        float inv = 1.0f;
        if (n < N) {
            int beg = offs[n], end = offs[n+1];
            inv = 1.0f / fmaxf((float)(end - beg), 1.0f);
            const float4* xb = (const float4*)x;      // 32 float4 per 128-dim row
            for (int p = beg; p < end; p++) {
                int pk = epack[p];
                int s  = pk & 0x1FFFF;
                int r  = pk >> 17;
                float4 v0 = xb[s*32 +      c];
                float4 v1 = xb[s*32 +  8 + c];
                float4 v2 = xb[s*32 + 16 + c];
                float4 v3 = xb[s*32 + 24 + c];
                float v[16] = { v0.x, v0.y, v0.z, v0.w,
                                v1.x, v1.y, v1.z, v1.w,
                                v2.x, v2.y, v2.z, v2.w,
                                v3.x, v3.y, v3.z, v3.w };
                float w0 = (r == 0) ? 1.f : 0.f;
                float w1 = (r == 1) ? 1.f : 0.f;
                float w2 = (r == 2) ? 1.f : 0.f;
                #pragma unroll
                for (int i = 0; i < 16; i++) {
                    a0[i] = fmaf(w0, v[i], a0[i]);
                    a1[i] = fmaf(w1, v[i], a1[i]);
                    a2[i] = fmaf(w2, v[i], a2[i]);
                }
            }
            xs[0] = xb[n*32 +      c];
            xs[1] = xb[n*32 +  8 + c];
            xs[2] = xb[n*32 + 16 + c];
            xs[3] = xb[n*32 + 24 + c];
        }
        float* Ar = &A[m*AST];
        #pragma unroll
        for (int seg = 0; seg < 4; seg++) {
            #pragma unroll
            for (int i = 0; i < 4; i++) {
                int dd = seg*32 + c*4 + i;
                Ar[0*DIM + dd] = a0[seg*4 + i] * inv;
                Ar[1*DIM + dd] = a1[seg*4 + i] * inv;
                Ar[2*DIM + dd] = a2[seg*4 + i] * inv;
            }
            float xv[4] = { xs[seg].x, xs[seg].y, xs[seg].z, xs[seg].w };
            #pragma unroll
            for (int i = 0; i < 4; i++)
                Ar[KS + seg*32 + c*4 + i] = xv[i];
        }
    }
    __syncthreads();

    // ---------------- MFMA GEMM (R5 verbatim) ----------------
    const int lane = t & 63;
    const int w    = t >> 6;                // 0..1 (wave)
    const int mm   = lane & 15;             // A row (node)
    const int q    = lane >> 4;             // k-octet selector
    f32x4 acc0 = {0,0,0,0}, acc1 = {0,0,0,0}, acc2 = {0,0,0,0}, acc3 = {0,0,0,0};
    {
        const short8* Bq = (const short8*)Bpack;
        #pragma unroll
        for (int kk = 0; kk < 16; kk++) {
            const float* ap = &A[mm*AST + kk*32 + q*8];
            float4 f0 = *(const float4*)ap;
            float4 f1 = *(const float4*)(ap + 4);
            union { short8 s; unsigned short u[8]; } af;
            af.u[0] = f2bf(f0.x); af.u[1] = f2bf(f0.y);
            af.u[2] = f2bf(f0.z); af.u[3] = f2bf(f0.w);
            af.u[4] = f2bf(f1.x); af.u[5] = f2bf(f1.y);
            af.u[6] = f2bf(f1.z); af.u[7] = f2bf(f1.w);
            short8 b0 = Bq[((w*4 + 0)*16 + kk)*64 + lane];
            short8 b1 = Bq[((w*4 + 1)*16 + kk)*64 + lane];
            short8 b2 = Bq[((w*4 + 2)*16 + kk)*64 + lane];
            short8 b3 = Bq[((w*4 + 3)*16 + kk)*64 + lane];
            acc0 = __builtin_amdgcn_mfma_f32_16x16x32_bf16(af.s, b0, acc0, 0, 0, 0);
            acc1 = __builtin_amdgcn_mfma_f32_16x16x32_bf16(af.s, b1, acc1, 0, 0, 0);
            acc2 = __builtin_amdgcn_mfma_f32_16x16x32_bf16(af.s, b2, acc2, 0, 0, 0);
            acc3 = __builtin_amdgcn_mfma_f32_16x16x32_bf16(af.s, b3, acc3, 0, 0, 0);
        }
    }
    __syncthreads();                        // all A reads done; reuse as H

    float* H = A;                           // H[16][132]
    {
        // C/D layout: col = lane&15, row = (lane>>4)*4 + i
        int rb = q * 4;
        #pragma unroll
        for (int nt = 0; nt < 4; nt++) {
            int d = (w*4 + nt)*16 + mm;
            float lb = linb[d];
            f32x4 a = (nt == 0) ? acc0 : (nt == 1) ? acc1 : (nt == 2) ? acc2 : acc3;
            #pragma unroll
            for (int i = 0; i < 4; i++)
                H[(rb + i)*132 + d] = a[i] + lb;
        }
    }
    __syncthreads();

    // ---------------- LayerNorm stats ----------------
    {
        int j = t >> 3, p = t & 7;
        float s1 = 0.f, s2 = 0.f;
        const float* hr = &H[j*132 + p*16];
        #pragma unroll
        for (int i = 0; i < 16; i++) { float v = hr[i]; s1 += v; s2 += v*v; }
        #pragma unroll
        for (int off = 1; off < 8; off <<= 1) {
            s1 += __shfl_xor(s1, off);
            s2 += __shfl_xor(s2, off);
        }
        if (p == 0) {
            float mu  = s1 * (1.0f/DIM);
            float var = s2 * (1.0f/DIM) - mu*mu;
            s_mu[j] = mu;
            s_rs[j] = rsqrtf(var + LN_EPS);
        }
    }
    __syncthreads();

    // ---------------- output (fp32) ----------------
    {
        int d = t;
        float g = gamma[d];
        float b = beta[d];
        for (int j = 0; j < NB; j++) {
            int n = n0 + j;
            if (n < N) {
                float hv = H[j*132 + d];
                out[(size_t)n*DIM + d] = g * (hv - s_mu[j]) * s_rs[j] + b;
            }
        }
    }
}

extern "C" void kernel_launch(void* const* d_in, const int* in_sizes, int n_in,
                              void* d_out, int out_size, void* d_ws, size_t ws_size,
                              hipStream_t stream)
{
    const float* x   = (const float*)d_in[0];
    const int*   ei  = (const int*)d_in[1];
    const int*   et  = (const int*)d_in[2];
    const float* rw  = (const float*)d_in[3];
    const float* lw  = (const float*)d_in[4];
    const float* lb  = (const float*)d_in[5];
    const float* lg  = (const float*)d_in[6];
    const float* lbe = (const float*)d_in[7];

    const int N = in_sizes[0] / DIM;
    const int E = in_sizes[2];

    // ws layout — same footprint class as R2/R5 (known good, ~3.13 MB)
    char* w = (char*)d_ws;
    int* flags = (int*)w;                 w += 16;
    int* cnt   = (int*)w;                 w += (size_t)N * 4;
    int* offs  = (int*)w;                 w += (size_t)(N+1) * 4;
    int* cur   = (int*)w;                 w += (size_t)N * 4;
    int* epack = (int*)w;                 w += (size_t)E * 4;
    w = (char*)(((uintptr_t)w + 15) & ~(uintptr_t)15);
    unsigned short* Bpack = (unsigned short*)w;    // 512*128 bf16 = 128 KiB

    hipMemsetAsync(cnt, 0, (size_t)N * 4, stream);
    probe_kernel<<<1, 64, 0, stream>>>(ei, flags);
    hist_kernel<<<(E + 255)/256, 256, 0, stream>>>(ei, E, cnt, flags);
    scan_kernel<<<1, 1024, 0, stream>>>(cnt, offs, cur, N);
    fill_kernel<<<(E + 255)/256, 256, 0, stream>>>(ei, et, E, cur, epack, flags);
    build_b<<<32, 256, 0, stream>>>(rw, lw, Bpack);

    main_kernel<<<(N + NB - 1)/NB, 128, 0, stream>>>(x, offs, epack, Bpack,
                                                     lb, lg, lbe,
                                                     (float*)d_out, N);
}

// Round 9
// 243.128 us; speedup vs baseline: 2.8588x; 1.3983x over previous
//
#include <hip/hip_runtime.h>
#include <hip/hip_bf16.h>

#define DIM   128
#define NREL  3
#define KS    (NREL*DIM)     // 384
#define KTOT  (KS + DIM)     // 512
#define NB    16             // nodes per block in main kernel
#define AST   (KTOT + 8)     // padded LDS row stride (floats)
#define LN_EPS 1e-5f
#define SCHUNK 1024          // scan elements per block

typedef unsigned int uint;
typedef float f32x4 __attribute__((ext_vector_type(4)));
typedef short short8 __attribute__((ext_vector_type(8)));

__device__ __forceinline__ unsigned short f2bf(float f) {   // round-to-nearest-even
    union { float f; uint u; } c; c.f = f;
    return (unsigned short)((c.u + 0x7fffu + ((c.u >> 16) & 1u)) >> 16);
}
// Index element i from an "int" input that may really be int64 (i64 flag)
__device__ __forceinline__ int ldidx(const int* p, size_t i, int i64) {
    return i64 ? p[2*i] : p[i];
}

// ---------------------------------------------------------------------------
// Probe int width: int64 storage => ~half of first 256 words are zero highs.
// ---------------------------------------------------------------------------
__global__ void probe_kernel(const int* __restrict__ ei, int* __restrict__ flags)
{
    int t = threadIdx.x;                    // 64 threads
    int z = 0;
    #pragma unroll
    for (int i = 0; i < 4; i++) z += (ei[t*4 + i] == 0) ? 1 : 0;
    #pragma unroll
    for (int off = 1; off < 64; off <<= 1) z += __shfl_xor(z, off);
    if (t == 0) flags[0] = (z > 64) ? 1 : 0;
}

// ---------------------------------------------------------------------------
// Histogram of dst
// ---------------------------------------------------------------------------
__global__ void hist_kernel(const int* __restrict__ ei, int E,
                            int* __restrict__ cnt,
                            const int* __restrict__ flags)
{
    int e = blockIdx.x * blockDim.x + threadIdx.x;
    if (e >= E) return;
    int i64 = flags[0];
    int d = ldidx(ei, (size_t)E + e, i64);
    atomicAdd(&cnt[d], 1);
}

// ---------------------------------------------------------------------------
// Multi-block exclusive scan, pass 1: per-block sums of cnt chunks.
// 256 threads/block, int4 loads (4 elements/thread).
// ---------------------------------------------------------------------------
__global__ __launch_bounds__(256)
void scan_p1(const int* __restrict__ cnt, int* __restrict__ part, int M)
{
    __shared__ int red[256];
    int b = blockIdx.x, t = threadIdx.x;
    int base = b * SCHUNK + t * 4;
    int s = 0;
    if (base + 3 < M) {
        int4 v = *(const int4*)(cnt + base);
        s = v.x + v.y + v.z + v.w;
    } else {
        for (int i = 0; i < 4; i++) if (base + i < M) s += cnt[base + i];
    }
    red[t] = s;
    __syncthreads();
    for (int off = 128; off > 0; off >>= 1) {
        if (t < off) red[t] += red[t + off];
        __syncthreads();
    }
    if (t == 0) part[b] = red[0];
}

// ---------------------------------------------------------------------------
// Pass 2: single block scans part[0..NBLK) -> exclusive bases; offs[M] = total.
// ---------------------------------------------------------------------------
__global__ __launch_bounds__(256)
void scan_p2(int* __restrict__ part, int NBLK, int* __restrict__ offs, int M)
{
    __shared__ int sh[256];
    int t = threadIdx.x;
    sh[t] = (t < NBLK) ? part[t] : 0;
    __syncthreads();
    for (int off = 1; off < 256; off <<= 1) {
        int v = sh[t];
        int a = (t >= off) ? sh[t - off] : 0;
        __syncthreads();
        sh[t] = v + a;
        __syncthreads();
    }
    if (t < NBLK) part[t] = (t == 0) ? 0 : sh[t - 1];
    if (t == 0) offs[M] = sh[NBLK - 1];
}

// ---------------------------------------------------------------------------
// Pass 3: per-block local exclusive scan + base -> offs, cur.
// ---------------------------------------------------------------------------
__global__ __launch_bounds__(256)
void scan_p3(const int* __restrict__ cnt, const int* __restrict__ part,
             int* __restrict__ offs, int* __restrict__ cur, int M)
{
    __shared__ int sh[256];
    int b = blockIdx.x, t = threadIdx.x;
    int base = b * SCHUNK + t * 4;
    int v[4];
    int s = 0;
    #pragma unroll
    for (int i = 0; i < 4; i++) {
        v[i] = (base + i < M) ? cnt[base + i] : 0;
        s += v[i];
    }
    sh[t] = s;
    __syncthreads();
    for (int off = 1; off < 256; off <<= 1) {
        int x = sh[t];
        int a = (t >= off) ? sh[t - off] : 0;
        __syncthreads();
        sh[t] = x + a;
        __syncthreads();
    }
    int run = part[b] + ((t == 0) ? 0 : sh[t - 1]);
    #pragma unroll
    for (int i = 0; i < 4; i++) {
        if (base + i < M) { offs[base + i] = run; cur[base + i] = run; run += v[i]; }
    }
}

// ---------------------------------------------------------------------------
// Fill CSR slots: epack[slot] = src | (type<<17)
// ---------------------------------------------------------------------------
__global__ void fill_kernel(const int* __restrict__ ei,
                            const int* __restrict__ et, int E,
                            int* __restrict__ cur,
                            int* __restrict__ epack,
                            const int* __restrict__ flags)
{
    int e = blockIdx.x * blockDim.x + threadIdx.x;
    if (e >= E) return;
    int i64 = flags[0];
    int s = ldidx(ei, (size_t)e, i64);
    int d = ldidx(ei, (size_t)E + e, i64);
    int r = ldidx(et, (size_t)e, i64);
    int p = atomicAdd(&cur[d], 1);
    epack[p] = s | (r << 17);
}

// ---------------------------------------------------------------------------
// Pack Wbig (fp32 in) into bf16 B-fragment order for mfma_f32_16x16x32_bf16.
// Wbig[k][n]: k<384 -> relation_weights[k*128+n]; k>=384 -> lin_w[n*128+(k-384)]
// ---------------------------------------------------------------------------
__global__ void build_b(const float* __restrict__ relw,
                        const float* __restrict__ linw,
                        unsigned short* __restrict__ Bpack)
{
    int idx = blockIdx.x * 256 + threadIdx.x;   // 0..8191 (16B slots)
    if (idx >= 8192) return;
    int lane = idx & 63, kk = (idx >> 6) & 15, tile = idx >> 10;
    int q = lane >> 4, n = tile * 16 + (lane & 15);
    uint vv[4];
    #pragma unroll
    for (int jp = 0; jp < 4; jp++) {
        int k0 = kk * 32 + q * 8 + jp * 2;
        float v0 = (k0     < KS) ? relw[(size_t)k0*DIM + n]
                                 : linw[(size_t)n*DIM + (k0 - KS)];
        float v1 = (k0 + 1 < KS) ? relw[(size_t)(k0+1)*DIM + n]
                                 : linw[(size_t)n*DIM + (k0 + 1 - KS)];
        vv[jp] = (uint)f2bf(v0) | ((uint)f2bf(v1) << 16);
    }
    uint4 v; v.x = vv[0]; v.y = vv[1]; v.z = vv[2]; v.w = vv[3];
    ((uint4*)Bpack)[idx] = v;
}

// ---------------------------------------------------------------------------
// Main (R8 verbatim): parallel gather (8 thr/node, float4 loads, mask-FMA) ->
// fp32 LDS A -> in-register bf16 A-frags -> MFMA vs Bpack -> +bias -> LN.
// ---------------------------------------------------------------------------
__global__ __launch_bounds__(128)
void main_kernel(const float* __restrict__ x,
                 const int* __restrict__ offs,
                 const int* __restrict__ epack,
                 const unsigned short* __restrict__ Bpack,
                 const float* __restrict__ linb,
                 const float* __restrict__ gamma,
                 const float* __restrict__ beta,
                 float* __restrict__ out,
                 int N)
{
    __shared__ float A[NB * AST];           // 33,280 B; reused as H[16][132]
    __shared__ float s_mu[NB], s_rs[NB];

    const int t  = threadIdx.x;             // 0..127
    const int n0 = blockIdx.x * NB;

    // ---------------- gather: 8 threads per node ----------------
    {
        const int m = t >> 3;               // node-local 0..15
        const int c = t & 7;                // float4 chunk
        const int n = n0 + m;
        float a0[16], a1[16], a2[16];
        #pragma unroll
        for (int i = 0; i < 16; i++) { a0[i] = 0.f; a1[i] = 0.f; a2[i] = 0.f; }
        float4 xs[4] = { {0,0,0,0}, {0,0,0,0}, {0,0,0,0}, {0,0,0,0} };
        float inv = 1.0f;
        if (n < N) {
            int beg = offs[n], end = offs[n+1];
            inv = 1.0f / fmaxf((float)(end - beg), 1.0f);
            const float4* xb = (const float4*)x;      // 32 float4 per row
            for (int p = beg; p < end; p++) {
                int pk = epack[p];
                int s  = pk & 0x1FFFF;
                int r  = pk >> 17;
                float4 v0 = xb[s*32 +      c];
                float4 v1 = xb[s*32 +  8 + c];
                float4 v2 = xb[s*32 + 16 + c];
                float4 v3 = xb[s*32 + 24 + c];
                float v[16] = { v0.x, v0.y, v0.z, v0.w,
                                v1.x, v1.y, v1.z, v1.w,
                                v2.x, v2.y, v2.z, v2.w,
                                v3.x, v3.y, v3.z, v3.w };
                float w0 = (r == 0) ? 1.f : 0.f;
                float w1 = (r == 1) ? 1.f : 0.f;
                float w2 = (r == 2) ? 1.f : 0.f;
                #pragma unroll
                for (int i = 0; i < 16; i++) {
                    a0[i] = fmaf(w0, v[i], a0[i]);
                    a1[i] = fmaf(w1, v[i], a1[i]);
                    a2[i] = fmaf(w2, v[i], a2[i]);
                }
            }
            xs[0] = xb[n*32 +      c];
            xs[1] = xb[n*32 +  8 + c];
            xs[2] = xb[n*32 + 16 + c];
            xs[3] = xb[n*32 + 24 + c];
        }
        float* Ar = &A[m*AST];
        #pragma unroll
        for (int seg = 0; seg < 4; seg++) {
            #pragma unroll
            for (int i = 0; i < 4; i++) {
                int dd = seg*32 + c*4 + i;
                Ar[0*DIM + dd] = a0[seg*4 + i] * inv;
                Ar[1*DIM + dd] = a1[seg*4 + i] * inv;
                Ar[2*DIM + dd] = a2[seg*4 + i] * inv;
            }
            float xv[4] = { xs[seg].x, xs[seg].y, xs[seg].z, xs[seg].w };
            #pragma unroll
            for (int i = 0; i < 4; i++)
                Ar[KS + seg*32 + c*4 + i] = xv[i];
        }
    }
    __syncthreads();

    // ---------------- MFMA GEMM ----------------
    const int lane = t & 63;
    const int w    = t >> 6;                // 0..1 (wave)
    const int mm   = lane & 15;             // A row (node)
    const int q    = lane >> 4;             // k-octet selector
    f32x4 acc0 = {0,0,0,0}, acc1 = {0,0,0,0}, acc2 = {0,0,0,0}, acc3 = {0,0,0,0};
    {
        const short8* Bq = (const short8*)Bpack;
        #pragma unroll
        for (int kk = 0; kk < 16; kk++) {
            const float* ap = &A[mm*AST + kk*32 + q*8];
            float4 f0 = *(const float4*)ap;
            float4 f1 = *(const float4*)(ap + 4);
            union { short8 s; unsigned short u[8]; } af;
            af.u[0] = f2bf(f0.x); af.u[1] = f2bf(f0.y);
            af.u[2] = f2bf(f0.z); af.u[3] = f2bf(f0.w);
            af.u[4] = f2bf(f1.x); af.u[5] = f2bf(f1.y);
            af.u[6] = f2bf(f1.z); af.u[7] = f2bf(f1.w);
            short8 b0 = Bq[((w*4 + 0)*16 + kk)*64 + lane];
            short8 b1 = Bq[((w*4 + 1)*16 + kk)*64 + lane];
            short8 b2 = Bq[((w*4 + 2)*16 + kk)*64 + lane];
            short8 b3 = Bq[((w*4 + 3)*16 + kk)*64 + lane];
            acc0 = __builtin_amdgcn_mfma_f32_16x16x32_bf16(af.s, b0, acc0, 0, 0, 0);
            acc1 = __builtin_amdgcn_mfma_f32_16x16x32_bf16(af.s, b1, acc1, 0, 0, 0);
            acc2 = __builtin_amdgcn_mfma_f32_16x16x32_bf16(af.s, b2, acc2, 0, 0, 0);
            acc3 = __builtin_amdgcn_mfma_f32_16x16x32_bf16(af.s, b3, acc3, 0, 0, 0);
        }
    }
    __syncthreads();                        // all A reads done; reuse as H

    float* H = A;                           // H[16][132]
    {
        int rb = q * 4;
        #pragma unroll
        for (int nt = 0; nt < 4; nt++) {
            int d = (w*4 + nt)*16 + mm;
            float lb = linb[d];
            f32x4 a = (nt == 0) ? acc0 : (nt == 1) ? acc1 : (nt == 2) ? acc2 : acc3;
            #pragma unroll
            for (int i = 0; i < 4; i++)
                H[(rb + i)*132 + d] = a[i] + lb;
        }
    }
    __syncthreads();

    // ---------------- LayerNorm stats ----------------
    {
        int j = t >> 3, p = t & 7;
        float s1 = 0.f, s2 = 0.f;
        const float* hr = &H[j*132 + p*16];
        #pragma unroll
        for (int i = 0; i < 16; i++) { float v = hr[i]; s1 += v; s2 += v*v; }
        #pragma unroll
        for (int off = 1; off < 8; off <<= 1) {
            s1 += __shfl_xor(s1, off);
            s2 += __shfl_xor(s2, off);
        }
        if (p == 0) {
            float mu  = s1 * (1.0f/DIM);
            float var = s2 * (1.0f/DIM) - mu*mu;
            s_mu[j] = mu;
            s_rs[j] = rsqrtf(var + LN_EPS);
        }
    }
    __syncthreads();

    // ---------------- output (fp32) ----------------
    {
        int d = t;
        float g = gamma[d];
        float b = beta[d];
        for (int j = 0; j < NB; j++) {
            int n = n0 + j;
            if (n < N) {
                float hv = H[j*132 + d];
                out[(size_t)n*DIM + d] = g * (hv - s_mu[j]) * s_rs[j] + b;
            }
        }
    }
}

extern "C" void kernel_launch(void* const* d_in, const int* in_sizes, int n_in,
                              void* d_out, int out_size, void* d_ws, size_t ws_size,
                              hipStream_t stream)
{
    const float* x   = (const float*)d_in[0];
    const int*   ei  = (const int*)d_in[1];
    const int*   et  = (const int*)d_in[2];
    const float* rw  = (const float*)d_in[3];
    const float* lw  = (const float*)d_in[4];
    const float* lb  = (const float*)d_in[5];
    const float* lg  = (const float*)d_in[6];
    const float* lbe = (const float*)d_in[7];

    const int N = in_sizes[0] / DIM;
    const int E = in_sizes[2];
    const int NBLK = (N + SCHUNK - 1) / SCHUNK;    // 49 for N=50000 (≤256)

    // ws layout — same footprint class as R8 (known good) + part[256]
    char* w = (char*)d_ws;
    int* flags = (int*)w;                 w += 16;
    int* part  = (int*)w;                 w += 256 * 4;
    int* cnt   = (int*)w;                 w += (size_t)N * 4;
    int* offs  = (int*)w;                 w += (size_t)(N+1) * 4;
    int* cur   = (int*)w;                 w += (size_t)N * 4;
    int* epack = (int*)w;                 w += (size_t)E * 4;
    w = (char*)(((uintptr_t)w + 15) & ~(uintptr_t)15);
    unsigned short* Bpack = (unsigned short*)w;    // 512*128 bf16 = 128 KiB

    hipMemsetAsync(cnt, 0, (size_t)N * 4, stream);
    probe_kernel<<<1, 64, 0, stream>>>(ei, flags);
    hist_kernel<<<(E + 255)/256, 256, 0, stream>>>(ei, E, cnt, flags);
    scan_p1<<<NBLK, 256, 0, stream>>>(cnt, part, N);
    scan_p2<<<1, 256, 0, stream>>>(part, NBLK, offs, N);
    scan_p3<<<NBLK, 256, 0, stream>>>(cnt, part, offs, cur, N);
    fill_kernel<<<(E + 255)/256, 256, 0, stream>>>(ei, et, E, cur, epack, flags);
    build_b<<<32, 256, 0, stream>>>(rw, lw, Bpack);

    main_kernel<<<(N + NB - 1)/NB, 128, 0, stream>>>(x, offs, epack, Bpack,
                                                     lb, lg, lbe,
                                                     (float*)d_out, N);
}

// Round 10
// 221.962 us; speedup vs baseline: 3.1314x; 1.0954x over previous
//
#include <hip/hip_runtime.h>
#include <hip/hip_bf16.h>

#define DIM   128
#define NREL  3
#define KS    (NREL*DIM)     // 384
#define NB    16             // nodes per block in main kernel
#define LN_EPS 1e-5f
#define SCHUNK 1024          // scan elements per block

typedef unsigned int uint;
typedef float f32x4 __attribute__((ext_vector_type(4)));
typedef short short8 __attribute__((ext_vector_type(8)));

__device__ __forceinline__ unsigned short f2bf(float f) {   // round-to-nearest-even
    union { float f; uint u; } c; c.f = f;
    return (unsigned short)((c.u + 0x7fffu + ((c.u >> 16) & 1u)) >> 16);
}
__device__ __forceinline__ uint packbf(float a, float b) {
    return (uint)f2bf(a) | ((uint)f2bf(b) << 16);
}
// Index element i from an "int" input that may really be int64 (i64 flag)
__device__ __forceinline__ int ldidx(const int* p, size_t i, int i64) {
    return i64 ? p[2*i] : p[i];
}
// 16B-slot offset of A-frag holding A[m][k..k+7] (k%8==0), 16-row tile,
// mfma_f32_16x16x32_bf16: slot = (k>>5)*64 + ((k>>3)&3)*16 + m
__device__ __forceinline__ int fo(int m, int k) {
    return ((k >> 5) << 6) + ((((k >> 3) & 3)) << 4) + m;
}

// ---------------------------------------------------------------------------
// Probe int width: int64 storage => ~half of first 256 words are zero highs.
// ---------------------------------------------------------------------------
__global__ void probe_kernel(const int* __restrict__ ei, int* __restrict__ flags)
{
    int t = threadIdx.x;                    // 64 threads
    int z = 0;
    #pragma unroll
    for (int i = 0; i < 4; i++) z += (ei[t*4 + i] == 0) ? 1 : 0;
    #pragma unroll
    for (int off = 1; off < 64; off <<= 1) z += __shfl_xor(z, off);
    if (t == 0) flags[0] = (z > 64) ? 1 : 0;
}

// ---------------------------------------------------------------------------
// FAST prologue: one pass converts indices and histograms dst.
// pk[e] = src | (rel<<17); dst32[e] = dst; cnt[dst]++.
// ---------------------------------------------------------------------------
__global__ void prep_kernel(const int* __restrict__ ei, const int* __restrict__ et,
                            int E, int* __restrict__ cnt,
                            int* __restrict__ dst32, int* __restrict__ pk,
                            const int* __restrict__ flags)
{
    int e = blockIdx.x * blockDim.x + threadIdx.x;
    if (e >= E) return;
    int i64 = flags[0];
    int s = ldidx(ei, (size_t)e, i64);
    int d = ldidx(ei, (size_t)E + e, i64);
    int r = ldidx(et, (size_t)e, i64);
    dst32[e] = d;
    pk[e] = s | (r << 17);
    atomicAdd(&cnt[d], 1);
}
// FAST fill: 8B/edge reads, atomic cursor, scatter epack.
__global__ void fillf_kernel(const int* __restrict__ dst32, const int* __restrict__ pk,
                             int E, int* __restrict__ cur, int* __restrict__ epack)
{
    int e = blockIdx.x * blockDim.x + threadIdx.x;
    if (e >= E) return;
    int p = atomicAdd(&cur[dst32[e]], 1);
    epack[p] = pk[e];
}

// ---------------------------------------------------------------------------
// FALLBACK prologue (R9-proven): hist + fill reading raw inputs.
// ---------------------------------------------------------------------------
__global__ void hist_kernel(const int* __restrict__ ei, int E,
                            int* __restrict__ cnt, const int* __restrict__ flags)
{
    int e = blockIdx.x * blockDim.x + threadIdx.x;
    if (e >= E) return;
    int d = ldidx(ei, (size_t)E + e, flags[0]);
    atomicAdd(&cnt[d], 1);
}
__global__ void fill_kernel(const int* __restrict__ ei, const int* __restrict__ et,
                            int E, int* __restrict__ cur, int* __restrict__ epack,
                            const int* __restrict__ flags)
{
    int e = blockIdx.x * blockDim.x + threadIdx.x;
    if (e >= E) return;
    int i64 = flags[0];
    int s = ldidx(ei, (size_t)e, i64);
    int d = ldidx(ei, (size_t)E + e, i64);
    int r = ldidx(et, (size_t)e, i64);
    int p = atomicAdd(&cur[d], 1);
    epack[p] = s | (r << 17);
}

// ---------------------------------------------------------------------------
// Scan pass 1: per-block sums of cnt chunks.
// ---------------------------------------------------------------------------
__global__ __launch_bounds__(256)
void scan_p1(const int* __restrict__ cnt, int* __restrict__ part, int M)
{
    __shared__ int red[256];
    int b = blockIdx.x, t = threadIdx.x;
    int base = b * SCHUNK + t * 4;
    int s = 0;
    if (base + 3 < M) {
        int4 v = *(const int4*)(cnt + base);
        s = v.x + v.y + v.z + v.w;
    } else {
        for (int i = 0; i < 4; i++) if (base + i < M) s += cnt[base + i];
    }
    red[t] = s;
    __syncthreads();
    for (int off = 128; off > 0; off >>= 1) {
        if (t < off) red[t] += red[t + off];
        __syncthreads();
    }
    if (t == 0) part[b] = red[0];
}

// ---------------------------------------------------------------------------
// Scan pass 2+3 fused: every block re-scans the (<=256) partials in-shared,
// then local exclusive scan + base -> offs, cur. Block 0 writes offs[M].
// ---------------------------------------------------------------------------
__global__ __launch_bounds__(256)
void scan_p23(const int* __restrict__ cnt, const int* __restrict__ part,
              int* __restrict__ offs, int* __restrict__ cur, int M, int NBLK)
{
    __shared__ int shp[256];
    __shared__ int sh[256];
    int b = blockIdx.x, t = threadIdx.x;
    shp[t] = (t < NBLK) ? part[t] : 0;
    __syncthreads();
    for (int off = 1; off < 256; off <<= 1) {
        int v = shp[t];
        int a = (t >= off) ? shp[t - off] : 0;
        __syncthreads();
        shp[t] = v + a;
        __syncthreads();
    }
    int base_b = (b == 0) ? 0 : shp[b - 1];
    if (b == 0 && t == 0) offs[M] = shp[NBLK - 1];

    int base = b * SCHUNK + t * 4;
    int v[4]; int s = 0;
    #pragma unroll
    for (int i = 0; i < 4; i++) {
        v[i] = (base + i < M) ? cnt[base + i] : 0;
        s += v[i];
    }
    sh[t] = s;
    __syncthreads();
    for (int off = 1; off < 256; off <<= 1) {
        int x = sh[t];
        int a = (t >= off) ? sh[t - off] : 0;
        __syncthreads();
        sh[t] = x + a;
        __syncthreads();
    }
    int run = base_b + ((t == 0) ? 0 : sh[t - 1]);
    #pragma unroll
    for (int i = 0; i < 4; i++) {
        if (base + i < M) { offs[base + i] = run; cur[base + i] = run; run += v[i]; }
    }
}

// ---------------------------------------------------------------------------
// Pack Wbig (fp32 in) into bf16 B-fragment order for mfma_f32_16x16x32_bf16.
// ---------------------------------------------------------------------------
__global__ void build_b(const float* __restrict__ relw,
                        const float* __restrict__ linw,
                        unsigned short* __restrict__ Bpack)
{
    int idx = blockIdx.x * 256 + threadIdx.x;   // 0..8191 (16B slots)
    if (idx >= 8192) return;
    int lane = idx & 63, kk = (idx >> 6) & 15, tile = idx >> 10;
    int q = lane >> 4, n = tile * 16 + (lane & 15);
    uint vv[4];
    #pragma unroll
    for (int jp = 0; jp < 4; jp++) {
        int k0 = kk * 32 + q * 8 + jp * 2;
        float v0 = (k0     < KS) ? relw[(size_t)k0*DIM + n]
                                 : linw[(size_t)n*DIM + (k0 - KS)];
        float v1 = (k0 + 1 < KS) ? relw[(size_t)(k0+1)*DIM + n]
                                 : linw[(size_t)n*DIM + (k0 + 1 - KS)];
        vv[jp] = packbf(v0, v1);
    }
    uint4 v; v.x = vv[0]; v.y = vv[1]; v.z = vv[2]; v.w = vv[3];
    ((uint4*)Bpack)[idx] = v;
}

// ---------------------------------------------------------------------------
// Main v2: gather (8 thr/node, 16 contiguous dims each, 2-way edge unroll)
// -> bf16 A-frags in LDS (16KB) -> MFMA -> +bias -> LN -> fp32 out.
// ---------------------------------------------------------------------------
__global__ __launch_bounds__(128)
void main_kernel(const float* __restrict__ x,
                 const int* __restrict__ offs,
                 const int* __restrict__ epack,
                 const unsigned short* __restrict__ Bpack,
                 const float* __restrict__ linb,
                 const float* __restrict__ gamma,
                 const float* __restrict__ beta,
                 float* __restrict__ out,
                 int N)
{
    __shared__ uint4 Af[1024];              // 16 KiB: A-frags, reused as H[16][132] fp32
    __shared__ float s_mu[NB], s_rs[NB];

    const int t  = threadIdx.x;             // 0..127
    const int n0 = blockIdx.x * NB;

    // ---------------- gather ----------------
    {
        const int m = t >> 3;               // node-local 0..15
        const int c = t & 7;                // owns dims [16c, 16c+16)
        const int n = n0 + m;
        float a0[16], a1[16], a2[16];
        #pragma unroll
        for (int i = 0; i < 16; i++) { a0[i] = 0.f; a1[i] = 0.f; a2[i] = 0.f; }
        float xf[16];
        #pragma unroll
        for (int i = 0; i < 16; i++) xf[i] = 0.f;
        float inv = 1.0f;
        if (n < N) {
            int beg = offs[n], end = offs[n+1];
            inv = 1.0f / fmaxf((float)(end - beg), 1.0f);
            const float4* xb = (const float4*)x;      // 32 float4 per row
            int p = beg;
            // 2-way unrolled edge loop for memory-level parallelism
            for (; p + 1 < end; p += 2) {
                int pk0 = epack[p], pk1 = epack[p+1];
                int s0 = pk0 & 0x1FFFF, r0 = pk0 >> 17;
                int s1 = pk1 & 0x1FFFF, r1 = pk1 >> 17;
                float4 u[4], v[4];
                #pragma unroll
                for (int i = 0; i < 4; i++) u[i] = xb[s0*32 + c*4 + i];
                #pragma unroll
                for (int i = 0; i < 4; i++) v[i] = xb[s1*32 + c*4 + i];
                float w00 = (r0==0)?1.f:0.f, w01 = (r0==1)?1.f:0.f, w02 = (r0==2)?1.f:0.f;
                float w10 = (r1==0)?1.f:0.f, w11 = (r1==1)?1.f:0.f, w12 = (r1==2)?1.f:0.f;
                #pragma unroll
                for (int i = 0; i < 4; i++) {
                    float uu[4] = { u[i].x, u[i].y, u[i].z, u[i].w };
                    float vv[4] = { v[i].x, v[i].y, v[i].z, v[i].w };
                    #pragma unroll
                    for (int l = 0; l < 4; l++) {
                        int j = 4*i + l;
                        a0[j] = fmaf(w00, uu[l], a0[j]);
                        a1[j] = fmaf(w01, uu[l], a1[j]);
                        a2[j] = fmaf(w02, uu[l], a2[j]);
                        a0[j] = fmaf(w10, vv[l], a0[j]);
                        a1[j] = fmaf(w11, vv[l], a1[j]);
                        a2[j] = fmaf(w12, vv[l], a2[j]);
                    }
                }
            }
            if (p < end) {
                int pk0 = epack[p];
                int s0 = pk0 & 0x1FFFF, r0 = pk0 >> 17;
                float4 u[4];
                #pragma unroll
                for (int i = 0; i < 4; i++) u[i] = xb[s0*32 + c*4 + i];
                float w00 = (r0==0)?1.f:0.f, w01 = (r0==1)?1.f:0.f, w02 = (r0==2)?1.f:0.f;
                #pragma unroll
                for (int i = 0; i < 4; i++) {
                    float uu[4] = { u[i].x, u[i].y, u[i].z, u[i].w };
                    #pragma unroll
                    for (int l = 0; l < 4; l++) {
                        int j = 4*i + l;
                        a0[j] = fmaf(w00, uu[l], a0[j]);
                        a1[j] = fmaf(w01, uu[l], a1[j]);
                        a2[j] = fmaf(w02, uu[l], a2[j]);
                    }
                }
            }
            #pragma unroll
            for (int i = 0; i < 4; i++) {
                float4 xv = xb[n*32 + c*4 + i];
                xf[4*i+0] = xv.x; xf[4*i+1] = xv.y; xf[4*i+2] = xv.z; xf[4*i+3] = xv.w;
            }
        }
        // write bf16 A-frags: dims [16c,16c+16) = two 8-dim frag slots per row
        {
            uint4 w0, w1;
            // r = 0
            w0.x = packbf(a0[0]*inv, a0[1]*inv);  w0.y = packbf(a0[2]*inv, a0[3]*inv);
            w0.z = packbf(a0[4]*inv, a0[5]*inv);  w0.w = packbf(a0[6]*inv, a0[7]*inv);
            w1.x = packbf(a0[8]*inv, a0[9]*inv);  w1.y = packbf(a0[10]*inv, a0[11]*inv);
            w1.z = packbf(a0[12]*inv, a0[13]*inv);w1.w = packbf(a0[14]*inv, a0[15]*inv);
            Af[fo(m, 0*DIM + 16*c)] = w0;  Af[fo(m, 0*DIM + 16*c + 8)] = w1;
            // r = 1
            w0.x = packbf(a1[0]*inv, a1[1]*inv);  w0.y = packbf(a1[2]*inv, a1[3]*inv);
            w0.z = packbf(a1[4]*inv, a1[5]*inv);  w0.w = packbf(a1[6]*inv, a1[7]*inv);
            w1.x = packbf(a1[8]*inv, a1[9]*inv);  w1.y = packbf(a1[10]*inv, a1[11]*inv);
            w1.z = packbf(a1[12]*inv, a1[13]*inv);w1.w = packbf(a1[14]*inv, a1[15]*inv);
            Af[fo(m, 1*DIM + 16*c)] = w0;  Af[fo(m, 1*DIM + 16*c + 8)] = w1;
            // r = 2
            w0.x = packbf(a2[0]*inv, a2[1]*inv);  w0.y = packbf(a2[2]*inv, a2[3]*inv);
            w0.z = packbf(a2[4]*inv, a2[5]*inv);  w0.w = packbf(a2[6]*inv, a2[7]*inv);
            w1.x = packbf(a2[8]*inv, a2[9]*inv);  w1.y = packbf(a2[10]*inv, a2[11]*inv);
            w1.z = packbf(a2[12]*inv, a2[13]*inv);w1.w = packbf(a2[14]*inv, a2[15]*inv);
            Af[fo(m, 2*DIM + 16*c)] = w0;  Af[fo(m, 2*DIM + 16*c + 8)] = w1;
            // x part
            w0.x = packbf(xf[0], xf[1]);   w0.y = packbf(xf[2], xf[3]);
            w0.z = packbf(xf[4], xf[5]);   w0.w = packbf(xf[6], xf[7]);
            w1.x = packbf(xf[8], xf[9]);   w1.y = packbf(xf[10], xf[11]);
            w1.z = packbf(xf[12], xf[13]); w1.w = packbf(xf[14], xf[15]);
            Af[fo(m, KS + 16*c)] = w0;     Af[fo(m, KS + 16*c + 8)] = w1;
        }
    }
    __syncthreads();

    // ---------------- MFMA GEMM ----------------
    const int lane = t & 63;
    const int w    = t >> 6;                // 0..1 (wave)
    const int mm   = lane & 15;
    const int q    = lane >> 4;
    f32x4 acc0 = {0,0,0,0}, acc1 = {0,0,0,0}, acc2 = {0,0,0,0}, acc3 = {0,0,0,0};
    {
        const short8* Aq = (const short8*)Af;
        const short8* Bq = (const short8*)Bpack;
        #pragma unroll
        for (int kk = 0; kk < 16; kk++) {
            short8 a  = Aq[kk*64 + lane];
            short8 b0 = Bq[((w*4 + 0)*16 + kk)*64 + lane];
            short8 b1 = Bq[((w*4 + 1)*16 + kk)*64 + lane];
            short8 b2 = Bq[((w*4 + 2)*16 + kk)*64 + lane];
            short8 b3 = Bq[((w*4 + 3)*16 + kk)*64 + lane];
            acc0 = __builtin_amdgcn_mfma_f32_16x16x32_bf16(a, b0, acc0, 0, 0, 0);
            acc1 = __builtin_amdgcn_mfma_f32_16x16x32_bf16(a, b1, acc1, 0, 0, 0);
            acc2 = __builtin_amdgcn_mfma_f32_16x16x32_bf16(a, b2, acc2, 0, 0, 0);
            acc3 = __builtin_amdgcn_mfma_f32_16x16x32_bf16(a, b3, acc3, 0, 0, 0);
        }
    }
    __syncthreads();                        // all A reads done; reuse as H

    float* H = (float*)Af;                  // H[16][132] = 8448 B < 16 KiB
    {
        int rb = q * 4;
        #pragma unroll
        for (int nt = 0; nt < 4; nt++) {
            int d = (w*4 + nt)*16 + mm;
            float lb = linb[d];
            f32x4 a = (nt == 0) ? acc0 : (nt == 1) ? acc1 : (nt == 2) ? acc2 : acc3;
            #pragma unroll
            for (int i = 0; i < 4; i++)
                H[(rb + i)*132 + d] = a[i] + lb;
        }
    }
    __syncthreads();

    // ---------------- LayerNorm stats ----------------
    {
        int j = t >> 3, p = t & 7;
        float s1 = 0.f, s2 = 0.f;
        const float* hr = &H[j*132 + p*16];
        #pragma unroll
        for (int i = 0; i < 16; i++) { float v = hr[i]; s1 += v; s2 += v*v; }
        #pragma unroll
        for (int off = 1; off < 8; off <<= 1) {
            s1 += __shfl_xor(s1, off);
            s2 += __shfl_xor(s2, off);
        }
        if (p == 0) {
            float mu  = s1 * (1.0f/DIM);
            float var = s2 * (1.0f/DIM) - mu*mu;
            s_mu[j] = mu;
            s_rs[j] = rsqrtf(var + LN_EPS);
        }
    }
    __syncthreads();

    // ---------------- output (fp32) ----------------
    {
        int d = t;
        float g = gamma[d];
        float b = beta[d];
        for (int j = 0; j < NB; j++) {
            int n = n0 + j;
            if (n < N) {
                float hv = H[j*132 + d];
                out[(size_t)n*DIM + d] = g * (hv - s_mu[j]) * s_rs[j] + b;
            }
        }
    }
}

extern "C" void kernel_launch(void* const* d_in, const int* in_sizes, int n_in,
                              void* d_out, int out_size, void* d_ws, size_t ws_size,
                              hipStream_t stream)
{
    const float* x   = (const float*)d_in[0];
    const int*   ei  = (const int*)d_in[1];
    const int*   et  = (const int*)d_in[2];
    const float* rw  = (const float*)d_in[3];
    const float* lw  = (const float*)d_in[4];
    const float* lb  = (const float*)d_in[5];
    const float* lg  = (const float*)d_in[6];
    const float* lbe = (const float*)d_in[7];

    const int N = in_sizes[0] / DIM;
    const int E = in_sizes[2];
    const int NBLK = (N + SCHUNK - 1) / SCHUNK;    // <= 256

    // ws layout — base identical to R9 (known good); optional fast-path tail
    char* w = (char*)d_ws;
    int* flags = (int*)w;                 w += 16;
    int* part  = (int*)w;                 w += 256 * 4;
    int* cnt   = (int*)w;                 w += (size_t)N * 4;
    int* offs  = (int*)w;                 w += (size_t)(N+1) * 4;
    int* cur   = (int*)w;                 w += (size_t)N * 4;
    int* epack = (int*)w;                 w += (size_t)E * 4;
    w = (char*)(((uintptr_t)w + 15) & ~(uintptr_t)15);
    unsigned short* Bpack = (unsigned short*)w;    w += 512 * 128 * 2;
    w = (char*)(((uintptr_t)w + 15) & ~(uintptr_t)15);
    int* dst32 = (int*)w;                 w += (size_t)E * 4;
    int* pk    = (int*)w;                 w += (size_t)E * 4;
    size_t need_fast = (size_t)(w - (char*)d_ws);
    const bool fast = (ws_size >= need_fast);      // constant across calls

    hipMemsetAsync(cnt, 0, (size_t)N * 4, stream);
    probe_kernel<<<1, 64, 0, stream>>>(ei, flags);
    if (fast) {
        prep_kernel<<<(E + 255)/256, 256, 0, stream>>>(ei, et, E, cnt, dst32, pk, flags);
    } else {
        hist_kernel<<<(E + 255)/256, 256, 0, stream>>>(ei, E, cnt, flags);
    }
    scan_p1<<<NBLK, 256, 0, stream>>>(cnt, part, N);
    scan_p23<<<NBLK, 256, 0, stream>>>(cnt, part, offs, cur, N, NBLK);
    if (fast) {
        fillf_kernel<<<(E + 255)/256, 256, 0, stream>>>(dst32, pk, E, cur, epack);
    } else {
        fill_kernel<<<(E + 255)/256, 256, 0, stream>>>(ei, et, E, cur, epack, flags);
    }
    build_b<<<32, 256, 0, stream>>>(rw, lw, Bpack);

    main_kernel<<<(N + NB - 1)/NB, 128, 0, stream>>>(x, offs, epack, Bpack,
                                                     lb, lg, lbe,
                                                     (float*)d_out, N);
}

// Round 11
// 213.631 us; speedup vs baseline: 3.2535x; 1.0390x over previous
//
#include <hip/hip_runtime.h>
#include <hip/hip_bf16.h>

#define DIM   128
#define NREL  3
#define KS    (NREL*DIM)     // 384
#define NB    16             // nodes per block in main kernel
#define LN_EPS 1e-5f
#define SCHUNK 1024          // scan elements per block

typedef unsigned int uint;
typedef float f32x4 __attribute__((ext_vector_type(4)));
typedef short short8 __attribute__((ext_vector_type(8)));

__device__ __forceinline__ unsigned short f2bf(float f) {   // round-to-nearest-even
    union { float f; uint u; } c; c.f = f;
    return (unsigned short)((c.u + 0x7fffu + ((c.u >> 16) & 1u)) >> 16);
}
__device__ __forceinline__ uint packbf(float a, float b) {
    return (uint)f2bf(a) | ((uint)f2bf(b) << 16);
}
// Index element i from an "int" input that may really be int64 (i64 flag)
__device__ __forceinline__ int ldidx(const int* p, size_t i, int i64) {
    return i64 ? p[2*i] : p[i];
}
// 16B-slot offset of A-frag holding A[m][k..k+7] (k%8==0), 16-row tile,
// mfma_f32_16x16x32_bf16: slot = (k>>5)*64 + ((k>>3)&3)*16 + m
__device__ __forceinline__ int fo(int m, int k) {
    return ((k >> 5) << 6) + ((((k >> 3) & 3)) << 4) + m;
}
// Bank swizzle: XOR bits>=4 into bits 0-2. Bijective; kills the 8-way
// same-m write conflict (write banks become m^f(c), f(c) in {0,2,4,6})
// while leaving the MFMA read distribution at the free 2-lanes/bank.
__device__ __forceinline__ int SW(int s) { return s ^ ((s >> 4) & 7); }

// ---------------------------------------------------------------------------
// Probe int width: int64 storage => ~half of first 256 words are zero highs.
// ---------------------------------------------------------------------------
__global__ void probe_kernel(const int* __restrict__ ei, int* __restrict__ flags)
{
    int t = threadIdx.x;                    // 64 threads
    int z = 0;
    #pragma unroll
    for (int i = 0; i < 4; i++) z += (ei[t*4 + i] == 0) ? 1 : 0;
    #pragma unroll
    for (int off = 1; off < 64; off <<= 1) z += __shfl_xor(z, off);
    if (t == 0) flags[0] = (z > 64) ? 1 : 0;
}

// ---------------------------------------------------------------------------
// FAST prologue: one pass converts indices + histograms (dst,rel) buckets.
// ---------------------------------------------------------------------------
__global__ void prep_kernel(const int* __restrict__ ei, const int* __restrict__ et,
                            int E, int* __restrict__ work,
                            int* __restrict__ dst3, int* __restrict__ src32,
                            const int* __restrict__ flags)
{
    int e = blockIdx.x * blockDim.x + threadIdx.x;
    if (e >= E) return;
    int i64 = flags[0];
    int s = ldidx(ei, (size_t)e, i64);
    int d = ldidx(ei, (size_t)E + e, i64);
    int r = ldidx(et, (size_t)e, i64);
    int b = d * 3 + r;
    dst3[e] = b;
    src32[e] = s;
    atomicAdd(&work[b], 1);
}
__global__ void fillf_kernel(const int* __restrict__ dst3, const int* __restrict__ src32,
                             int E, int* __restrict__ work, int* __restrict__ epack)
{
    int e = blockIdx.x * blockDim.x + threadIdx.x;
    if (e >= E) return;
    int p = atomicAdd(&work[dst3[e]], 1);
    epack[p] = src32[e];
}

// ---------------------------------------------------------------------------
// FALLBACK prologue: hist + fill reading raw ei/et (3.13 MB ws total).
// ---------------------------------------------------------------------------
__global__ void hist_kernel(const int* __restrict__ ei, const int* __restrict__ et,
                            int E, int* __restrict__ work, const int* __restrict__ flags)
{
    int e = blockIdx.x * blockDim.x + threadIdx.x;
    if (e >= E) return;
    int i64 = flags[0];
    int d = ldidx(ei, (size_t)E + e, i64);
    int r = ldidx(et, (size_t)e, i64);
    atomicAdd(&work[d * 3 + r], 1);
}
__global__ void fill_kernel(const int* __restrict__ ei, const int* __restrict__ et,
                            int E, int* __restrict__ work, int* __restrict__ epack,
                            const int* __restrict__ flags)
{
    int e = blockIdx.x * blockDim.x + threadIdx.x;
    if (e >= E) return;
    int i64 = flags[0];
    int s = ldidx(ei, (size_t)e, i64);
    int d = ldidx(ei, (size_t)E + e, i64);
    int r = ldidx(et, (size_t)e, i64);
    int p = atomicAdd(&work[d * 3 + r], 1);
    epack[p] = s;
}

// ---------------------------------------------------------------------------
// Scan pass 1 (per-block sums of work) + fused B-pack (independent work).
// ---------------------------------------------------------------------------
__global__ __launch_bounds__(256)
void scan_p1(const int* __restrict__ work, int* __restrict__ part, int M,
             const float* __restrict__ relw, const float* __restrict__ linw,
             unsigned short* __restrict__ Bpack)
{
    __shared__ int red[256];
    int b = blockIdx.x, t = threadIdx.x;
    int base = b * SCHUNK + t * 4;
    int s = 0;
    if (base + 3 < M) {
        int4 v = *(const int4*)(work + base);
        s = v.x + v.y + v.z + v.w;
    } else {
        for (int i = 0; i < 4; i++) if (base + i < M) s += work[base + i];
    }
    red[t] = s;
    __syncthreads();
    for (int off = 128; off > 0; off >>= 1) {
        if (t < off) red[t] += red[t + off];
        __syncthreads();
    }
    if (t == 0) part[b] = red[0];

    // ---- fused build_b: pack Wbig (fp32) into bf16 B-fragment order ----
    // Wbig[k][n]: k<384 -> relation_weights[k*128+n]; k>=384 -> lin_w[n*128+(k-384)]
    for (int idx = b * 256 + t; idx < 8192; idx += gridDim.x * 256) {
        int lane = idx & 63, kk = (idx >> 6) & 15, tile = idx >> 10;
        int q = lane >> 4, n = tile * 16 + (lane & 15);
        uint vv[4];
        #pragma unroll
        for (int jp = 0; jp < 4; jp++) {
            int k0 = kk * 32 + q * 8 + jp * 2;
            float v0 = (k0     < KS) ? relw[(size_t)k0*DIM + n]
                                     : linw[(size_t)n*DIM + (k0 - KS)];
            float v1 = (k0 + 1 < KS) ? relw[(size_t)(k0+1)*DIM + n]
                                     : linw[(size_t)n*DIM + (k0 + 1 - KS)];
            vv[jp] = packbf(v0, v1);
        }
        uint4 v; v.x = vv[0]; v.y = vv[1]; v.z = vv[2]; v.w = vv[3];
        ((uint4*)Bpack)[idx] = v;
    }
}

// ---------------------------------------------------------------------------
// Scan pass 2+3 fused, IN PLACE: re-scan partials, local scan, write starts
// back into work. After fill's atomic advance, work[b] == end of bucket b.
// Requires NBLK <= 256 (M=150000 -> 147).
// ---------------------------------------------------------------------------
__global__ __launch_bounds__(256)
void scan_p23(int* __restrict__ work, const int* __restrict__ part, int M, int NBLK)
{
    __shared__ int shp[256];
    __shared__ int sh[256];
    int b = blockIdx.x, t = threadIdx.x;
    shp[t] = (t < NBLK) ? part[t] : 0;
    __syncthreads();
    for (int off = 1; off < 256; off <<= 1) {
        int v = shp[t];
        int a = (t >= off) ? shp[t - off] : 0;
        __syncthreads();
        shp[t] = v + a;
        __syncthreads();
    }
    int base_b = (b == 0) ? 0 : shp[b - 1];

    int base = b * SCHUNK + t * 4;
    int v[4]; int s = 0;
    #pragma unroll
    for (int i = 0; i < 4; i++) {
        v[i] = (base + i < M) ? work[base + i] : 0;
        s += v[i];
    }
    sh[t] = s;
    __syncthreads();
    for (int off = 1; off < 256; off <<= 1) {
        int x = sh[t];
        int a = (t >= off) ? sh[t - off] : 0;
        __syncthreads();
        sh[t] = x + a;
        __syncthreads();
    }
    int run = base_b + ((t == 0) ? 0 : sh[t - 1]);
    #pragma unroll
    for (int i = 0; i < 4; i++) {
        if (base + i < M) { work[base + i] = run; run += v[i]; }
    }
}

// ---------------------------------------------------------------------------
// Main: bucketed gather (8 thr/node, single acc[16] per relation-run) ->
// swizzled bf16 A-frags in LDS (16KB) -> MFMA -> +bias -> LN -> fp32 out.
// ends[b] = end offset of bucket b; start = ends[b-1] (0 for b=0).
// ---------------------------------------------------------------------------
__global__ __launch_bounds__(128)
void main_kernel(const float* __restrict__ x,
                 const int* __restrict__ ends,
                 const int* __restrict__ epack,
                 const unsigned short* __restrict__ Bpack,
                 const float* __restrict__ linb,
                 const float* __restrict__ gamma,
                 const float* __restrict__ beta,
                 float* __restrict__ out,
                 int N)
{
    __shared__ uint4 Af[1024];              // 16 KiB: A-frags, reused as H[16][132]
    __shared__ float s_mu[NB], s_rs[NB];

    const int t  = threadIdx.x;             // 0..127
    const int n0 = blockIdx.x * NB;

    // ---------------- gather ----------------
    {
        const int m = t >> 3;               // node-local 0..15
        const int c = t & 7;                // owns dims [16c, 16c+16)
        const int c4 = c * 4;
        const int n = n0 + m;
        int beg[3] = {0,0,0}, en[3] = {0,0,0};
        float inv = 1.0f;
        float xf[16];
        #pragma unroll
        for (int i = 0; i < 16; i++) xf[i] = 0.f;
        const float4* xb = (const float4*)x;      // 32 float4 per 128-dim row
        if (n < N) {
            int b3 = n * 3;
            int p0 = (b3 == 0) ? 0 : ends[b3 - 1];
            int p1 = ends[b3], p2 = ends[b3 + 1], p3 = ends[b3 + 2];
            beg[0] = p0; en[0] = p1;
            beg[1] = p1; en[1] = p2;
            beg[2] = p2; en[2] = p3;
            inv = 1.0f / fmaxf((float)(p3 - p0), 1.0f);
            #pragma unroll
            for (int i = 0; i < 4; i++) {
                float4 xv = xb[n*32 + c4 + i];
                xf[4*i+0] = xv.x; xf[4*i+1] = xv.y; xf[4*i+2] = xv.z; xf[4*i+3] = xv.w;
            }
        }
        #pragma unroll
        for (int r = 0; r < NREL; r++) {
            float acc[16];
            #pragma unroll
            for (int i = 0; i < 16; i++) acc[i] = 0.f;
            int p = beg[r], pe = en[r];
            for (; p + 1 < pe; p += 2) {            // 2-way unroll for MLP
                int sA = epack[p], sB = epack[p+1];
                float4 u0 = xb[sA*32 + c4 + 0];
                float4 u1 = xb[sA*32 + c4 + 1];
                float4 u2 = xb[sA*32 + c4 + 2];
                float4 u3 = xb[sA*32 + c4 + 3];
                float4 v0 = xb[sB*32 + c4 + 0];
                float4 v1 = xb[sB*32 + c4 + 1];
                float4 v2 = xb[sB*32 + c4 + 2];
                float4 v3 = xb[sB*32 + c4 + 3];
                acc[0]  += u0.x + v0.x; acc[1]  += u0.y + v0.y;
                acc[2]  += u0.z + v0.z; acc[3]  += u0.w + v0.w;
                acc[4]  += u1.x + v1.x; acc[5]  += u1.y + v1.y;
                acc[6]  += u1.z + v1.z; acc[7]  += u1.w + v1.w;
                acc[8]  += u2.x + v2.x; acc[9]  += u2.y + v2.y;
                acc[10] += u2.z + v2.z; acc[11] += u2.w + v2.w;
                acc[12] += u3.x + v3.x; acc[13] += u3.y + v3.y;
                acc[14] += u3.z + v3.z; acc[15] += u3.w + v3.w;
            }
            if (p < pe) {
                int sA = epack[p];
                float4 u0 = xb[sA*32 + c4 + 0];
                float4 u1 = xb[sA*32 + c4 + 1];
                float4 u2 = xb[sA*32 + c4 + 2];
                float4 u3 = xb[sA*32 + c4 + 3];
                acc[0]  += u0.x; acc[1]  += u0.y; acc[2]  += u0.z; acc[3]  += u0.w;
                acc[4]  += u1.x; acc[5]  += u1.y; acc[6]  += u1.z; acc[7]  += u1.w;
                acc[8]  += u2.x; acc[9]  += u2.y; acc[10] += u2.z; acc[11] += u2.w;
                acc[12] += u3.x; acc[13] += u3.y; acc[14] += u3.z; acc[15] += u3.w;
            }
            uint4 w0, w1;
            w0.x = packbf(acc[0]*inv,  acc[1]*inv);  w0.y = packbf(acc[2]*inv,  acc[3]*inv);
            w0.z = packbf(acc[4]*inv,  acc[5]*inv);  w0.w = packbf(acc[6]*inv,  acc[7]*inv);
            w1.x = packbf(acc[8]*inv,  acc[9]*inv);  w1.y = packbf(acc[10]*inv, acc[11]*inv);
            w1.z = packbf(acc[12]*inv, acc[13]*inv); w1.w = packbf(acc[14]*inv, acc[15]*inv);
            int k = r*DIM + 16*c;
            Af[SW(fo(m, k))]     = w0;
            Af[SW(fo(m, k + 8))] = w1;
        }
        {
            uint4 w0, w1;
            w0.x = packbf(xf[0],  xf[1]);  w0.y = packbf(xf[2],  xf[3]);
            w0.z = packbf(xf[4],  xf[5]);  w0.w = packbf(xf[6],  xf[7]);
            w1.x = packbf(xf[8],  xf[9]);  w1.y = packbf(xf[10], xf[11]);
            w1.z = packbf(xf[12], xf[13]); w1.w = packbf(xf[14], xf[15]);
            int k = KS + 16*c;
            Af[SW(fo(m, k))]     = w0;
            Af[SW(fo(m, k + 8))] = w1;
        }
    }
    __syncthreads();

    // ---------------- MFMA GEMM ----------------
    const int lane = t & 63;
    const int w    = t >> 6;                // 0..1 (wave)
    const int mm   = lane & 15;
    const int q    = lane >> 4;
    f32x4 acc0 = {0,0,0,0}, acc1 = {0,0,0,0}, acc2 = {0,0,0,0}, acc3 = {0,0,0,0};
    {
        const short8* Aq = (const short8*)Af;
        const short8* Bq = (const short8*)Bpack;
        #pragma unroll
        for (int kk = 0; kk < 16; kk++) {
            short8 a  = Aq[SW(kk*64 + lane)];
            short8 b0 = Bq[((w*4 + 0)*16 + kk)*64 + lane];
            short8 b1 = Bq[((w*4 + 1)*16 + kk)*64 + lane];
            short8 b2 = Bq[((w*4 + 2)*16 + kk)*64 + lane];
            short8 b3 = Bq[((w*4 + 3)*16 + kk)*64 + lane];
            acc0 = __builtin_amdgcn_mfma_f32_16x16x32_bf16(a, b0, acc0, 0, 0, 0);
            acc1 = __builtin_amdgcn_mfma_f32_16x16x32_bf16(a, b1, acc1, 0, 0, 0);
            acc2 = __builtin_amdgcn_mfma_f32_16x16x32_bf16(a, b2, acc2, 0, 0, 0);
            acc3 = __builtin_amdgcn_mfma_f32_16x16x32_bf16(a, b3, acc3, 0, 0, 0);
        }
    }
    __syncthreads();                        // all A reads done; reuse as H

    float* H = (float*)Af;                  // H[16][132] = 8448 B < 16 KiB
    {
        int rb = q * 4;
        #pragma unroll
        for (int nt = 0; nt < 4; nt++) {
            int d = (w*4 + nt)*16 + mm;
            float lb = linb[d];
            f32x4 a = (nt == 0) ? acc0 : (nt == 1) ? acc1 : (nt == 2) ? acc2 : acc3;
            #pragma unroll
            for (int i = 0; i < 4; i++)
                H[(rb + i)*132 + d] = a[i] + lb;
        }
    }
    __syncthreads();

    // ---------------- LayerNorm stats ----------------
    {
        int j = t >> 3, p = t & 7;
        float s1 = 0.f, s2 = 0.f;
        const float* hr = &H[j*132 + p*16];
        #pragma unroll
        for (int i = 0; i < 16; i++) { float v = hr[i]; s1 += v; s2 += v*v; }
        #pragma unroll
        for (int off = 1; off < 8; off <<= 1) {
            s1 += __shfl_xor(s1, off);
            s2 += __shfl_xor(s2, off);
        }
        if (p == 0) {
            float mu  = s1 * (1.0f/DIM);
            float var = s2 * (1.0f/DIM) - mu*mu;
            s_mu[j] = mu;
            s_rs[j] = rsqrtf(var + LN_EPS);
        }
    }
    __syncthreads();

    // ---------------- output (fp32) ----------------
    {
        int d = t;
        float g = gamma[d];
        float b = beta[d];
        for (int j = 0; j < NB; j++) {
            int n = n0 + j;
            if (n < N) {
                float hv = H[j*132 + d];
                out[(size_t)n*DIM + d] = g * (hv - s_mu[j]) * s_rs[j] + b;
            }
        }
    }
}

extern "C" void kernel_launch(void* const* d_in, const int* in_sizes, int n_in,
                              void* d_out, int out_size, void* d_ws, size_t ws_size,
                              hipStream_t stream)
{
    const float* x   = (const float*)d_in[0];
    const int*   ei  = (const int*)d_in[1];
    const int*   et  = (const int*)d_in[2];
    const float* rw  = (const float*)d_in[3];
    const float* lw  = (const float*)d_in[4];
    const float* lb  = (const float*)d_in[5];
    const float* lg  = (const float*)d_in[6];
    const float* lbe = (const float*)d_in[7];

    const int N  = in_sizes[0] / DIM;
    const int E  = in_sizes[2];
    const int M3 = 3 * N;
    const int NBLK = (M3 + SCHUNK - 1) / SCHUNK;   // 147 for N=50000 (<=256)

    // ws layout — fallback footprint 3.13 MB (<= known-good 3.26 MB);
    // fast path adds dst3/src32 (4.8 MB) gated on ws_size.
    char* w = (char*)d_ws;
    int* flags = (int*)w;                 w += 16;
    int* part  = (int*)w;                 w += 256 * 4;
    int* work  = (int*)w;                 w += (size_t)M3 * 4;      // 600 KB
    int* epack = (int*)w;                 w += (size_t)E * 4;       // 2.4 MB
    w = (char*)(((uintptr_t)w + 15) & ~(uintptr_t)15);
    unsigned short* Bpack = (unsigned short*)w;    w += 512 * 128 * 2;  // 128 KB
    w = (char*)(((uintptr_t)w + 15) & ~(uintptr_t)15);
    int* dst3  = (int*)w;                 w += (size_t)E * 4;
    int* src32 = (int*)w;                 w += (size_t)E * 4;
    size_t need_fast = (size_t)(w - (char*)d_ws);
    const bool fast = (ws_size >= need_fast);      // constant across calls

    hipMemsetAsync(work, 0, (size_t)M3 * 4, stream);
    probe_kernel<<<1, 64, 0, stream>>>(ei, flags);
    if (fast) {
        prep_kernel<<<(E + 255)/256, 256, 0, stream>>>(ei, et, E, work, dst3, src32, flags);
    } else {
        hist_kernel<<<(E + 255)/256, 256, 0, stream>>>(ei, et, E, work, flags);
    }
    scan_p1<<<NBLK, 256, 0, stream>>>(work, part, M3, rw, lw, Bpack);
    scan_p23<<<NBLK, 256, 0, stream>>>(work, part, M3, NBLK);
    if (fast) {
        fillf_kernel<<<(E + 255)/256, 256, 0, stream>>>(dst3, src32, E, work, epack);
    } else {
        fill_kernel<<<(E + 255)/256, 256, 0, stream>>>(ei, et, E, work, epack, flags);
    }
    main_kernel<<<(N + NB - 1)/NB, 128, 0, stream>>>(x, work, epack, Bpack,
                                                     lb, lg, lbe,
                                                     (float*)d_out, N);
}